// Round 21
// baseline (219.934 us; speedup 1.0000x reference)
//
#include <hip/hip_runtime.h>
#include <hip/hip_bf16.h>
#include <stdint.h>

#define NB   32
#define CIN  256
#define COUT 256
#define WW   56
#define HW   3136
#define NEXP 3
#define KTOT 2304          // 9 * 256
#define XP   58
#define XPP  3364          // 58*58
#define NKT  36            // K-tiles of 64

typedef __attribute__((ext_vector_type(8))) __bf16 bf16x8;
typedef __attribute__((ext_vector_type(4))) float  f32x4;

// workspace layout (bytes)
#define OFF_RW     0
#define OFF_POOLED 1024
#define OFF_CWT    (1024 + 32*256*16*4)
#define CWT_BYTES  ((size_t)NB*COUT*KTOT*2)
#define OFF_XPAD   (OFF_CWT + CWT_BYTES)

// ---------------- fused prologue: xpad + pool + zborder (disjoint ranges) ---
#define PRE_XPAD 6272
#define PRE_POOL 8192
#define PRE_NBLK (PRE_XPAD + PRE_POOL + NB)

__global__ __launch_bounds__(256) void k_pre(const float* __restrict__ x,
                                             float* __restrict__ pooled,
                                             __bf16* __restrict__ xpad) {
    __shared__ __align__(16) char smem[8448];
    int blk = blockIdx.x;
    int t = threadIdx.x;

    if (blk < PRE_XPAD) {
        int pt = blk % 49;
        int r2 = blk / 49;
        int ct = r2 & 3;
        int b  = r2 >> 2;
        __bf16 (*lds)[66] = (__bf16(*)[66])smem;
        int pl = t & 63;
        int cb = t >> 6;
        const float* xb = x + ((size_t)(b * CIN + ct * 64)) * HW + pt * 64;
        #pragma unroll
        for (int ic = 0; ic < 16; ++ic) {
            int cl = ic * 4 + cb;
            lds[cl][pl] = (__bf16)xb[(size_t)cl * HW + pl];
        }
        __syncthreads();
        #pragma unroll
        for (int iw = 0; iw < 2; ++iw) {
            int idx = iw * 256 + t;
            int p_l = idx >> 3, c8 = (idx & 7) * 8;
            int p = pt * 64 + p_l;
            int y = p / WW, xx = p - y * WW;
            union { __bf16 h[8]; uint4 u; } pk;
            #pragma unroll
            for (int j = 0; j < 8; ++j) pk.h[j] = lds[c8 + j][p_l];
            __bf16* dst = xpad + ((size_t)b * XPP + (y + 1) * XP + (xx + 1)) * CIN
                          + ct * 64 + c8;
            *(uint4*)dst = pk.u;
        }
    } else if (blk < PRE_XPAD + PRE_POOL) {
        int j = blk - PRE_XPAD;
        int b = j >> 8, c = j & 255;
        float (*lds)[56] = (float(*)[56])smem;
        const float* xb = x + ((size_t)(b * CIN + c)) * HW;
        if (t < 224) {
            int xc = t % 56, yg = t / 56;
            const float* p = xb + (yg * 14) * WW + xc;
            float s = 0.f;
            #pragma unroll
            for (int r = 0; r < 14; ++r) s += p[r * WW];
            lds[yg][xc] = s;
        }
        __syncthreads();
        if (t < 16) {
            int sy = t >> 2, sx = t & 3;
            float s = 0.f;
            #pragma unroll
            for (int jj = 0; jj < 14; ++jj) s += lds[sy][sx * 14 + jj];
            pooled[(((size_t)b * CIN + c) << 4) + t] = s * (1.f / 196.f);
        }
    } else {
        int b = blk - (PRE_XPAD + PRE_POOL);
        for (int idx = t; idx < 228 * 32; idx += 256) {
            int pos = idx >> 5;
            int co = (idx & 31) * 8;
            int yy, xx;
            if (pos < 58)       { yy = 0;          xx = pos; }
            else if (pos < 116) { yy = 57;         xx = pos - 58; }
            else if (pos < 172) { yy = pos - 115;  xx = 0; }
            else                { yy = pos - 171;  xx = 57; }
            uint4 z = {0u, 0u, 0u, 0u};
            *(uint4*)(xpad + ((size_t)b * XPP + yy * XP + xx) * CIN + co) = z;
        }
    }
}

// ---------------- routing ---------------------------------------------------
__global__ __launch_bounds__(256) void k_route(const float* __restrict__ pooled,
                                               const float* __restrict__ rcw,
                                               const float* __restrict__ rcb,
                                               const float* __restrict__ fcw,
                                               const float* __restrict__ fcb,
                                               float* __restrict__ rw) {
    int b = blockIdx.x;
    int t = threadIdx.x;
    int r = t >> 4, ij = t & 15;
    __shared__ float rbuf[256];
    const float* pb = pooled + (size_t)b * CIN * 16;
    float acc = rcb[r];
    for (int c = 0; c < CIN; ++c)
        acc += pb[c * 16 + ij] * rcw[r * CIN + c];
    rbuf[t] = fmaxf(acc, 0.f);
    __syncthreads();
    if (t < NEXP) {
        float a = fcb[t];
        for (int f = 0; f < 256; ++f) a += rbuf[f] * fcw[t * 256 + f];
        a = fmaxf(a, 0.f);
        rw[b * NEXP + t] = 1.f / (1.f + expf(-a));
    }
}

// ---------------- weight mixing (LDS-staged, coalesced uint4 writes) --------
// One block per o. Stage we[e][o][:][:] (3 x 2304 floats = 27 KB) in LDS via
// coalesced float4 loads, then per sample write the 2304-element cwt row as
// 288 uint4 stores (8 bf16 each, fully coalesced). Replaces scalar 2B
// stores at stride 512B (R1-R20 version).
__global__ __launch_bounds__(256) void k_mixw(const float* __restrict__ we,
                                              const float* __restrict__ rw,
                                              __bf16* __restrict__ cwt) {
    __shared__ float lds[6912];          // [e][c*9+k]
    int o = blockIdx.x;
    int t = threadIdx.x;
    const float* base = we + (size_t)o * 2304;
    #pragma unroll
    for (int e = 0; e < 3; ++e) {
        const float4* src = (const float4*)(base + (size_t)e * 589824);
        float4* dst = (float4*)(lds + e * 2304);
        for (int i = t; i < 576; i += 256) dst[i] = src[i];
    }
    __syncthreads();
    for (int b = 0; b < NB; ++b) {
        float r0 = rw[b * 3 + 0], r1 = rw[b * 3 + 1], r2 = rw[b * 3 + 2];
        __bf16* op = cwt + ((size_t)(b * COUT + o)) * KTOT;
        for (int ch = t; ch < 288; ch += 256) {
            int k = ch >> 5, i0 = (ch & 31) * 8;   // row elem = k*256 + i
            union { __bf16 h[8]; uint4 u; } pk;
            #pragma unroll
            for (int j = 0; j < 8; ++j) {
                int idx = (i0 + j) * 9 + k;
                float v = r0 * lds[idx] + r1 * lds[2304 + idx]
                        + r2 * lds[4608 + idx];
                pk.h[j] = (__bf16)v;
            }
            *(uint4*)(op + ch * 8) = pk.u;
        }
    }
}

// ---------------- implicit-GEMM conv ----------------------------------------
// 256x256 tile, BK=64, 16 waves x 64x64 wave-tiles (best measured: R15,
// conv ~134us), 128 KiB LDS. Publication-shifted phase: {reads (c,kh) ->
// stages (o,kh) -> VMCNT(2) -> barrier -> lgkm0 -> 16-MFMA}. VMCNT(2)
// retires the pair staged in the PREVIOUS phase (the slabs the NEXT phase
// reads); the barrier publishes them (all-waves vmcnt + barrier = race-free).
// Outstanding/thread: 2 -> 4 -> VMCNT(2) -> 2. Prologue: 4 stages, VMCNT(2),
// barrier. Tail: VMCNT(0)+barrier between its two halves.
// WAR: slab overwrite-stage is 2 barriers after its last reads retired.
#define GL16(g, l) __builtin_amdgcn_global_load_lds( \
    (const __attribute__((address_space(1))) uint32_t*)(g), \
    (__attribute__((address_space(3))) uint32_t*)(l), 16, 0, 0)

#define STAGE_A(o, kh, aoffn) \
    GL16(gA + (aoffn) + (kh)*64, LDS + (o)*32768 + (kh)*16384 + wid*1024)
#define STAGE_B(o, kh, boffn) \
    GL16(gB + (boffn) + (kh)*64, LDS + 65536 + (o)*32768 + (kh)*16384 + wid*1024)

#define BARRIER() do { \
    __builtin_amdgcn_sched_barrier(0); \
    __builtin_amdgcn_s_barrier(); \
    __builtin_amdgcn_sched_barrier(0); \
  } while (0)
#define VMCNT(n) do { \
    asm volatile("s_waitcnt vmcnt(" #n ")" ::: "memory"); \
    __builtin_amdgcn_sched_barrier(0); \
  } while (0)
#define LGKM0() do { \
    asm volatile("s_waitcnt lgkmcnt(0)" ::: "memory"); \
    __builtin_amdgcn_sched_barrier(0); \
  } while (0)

#define LOAD4(F, base) do { \
    F[0] = *(const bf16x8*)((base) + 0); \
    F[1] = *(const bf16x8*)((base) + 1024); \
    F[2] = *(const bf16x8*)((base) + 2048); \
    F[3] = *(const bf16x8*)((base) + 3072); \
  } while (0)
#define MMALL() do { \
    __builtin_amdgcn_s_setprio(1); \
    _Pragma("unroll") \
    for (int mf = 0; mf < 4; ++mf) \
      _Pragma("unroll") \
      for (int nf = 0; nf < 4; ++nf) \
        acc[mf][nf] = __builtin_amdgcn_mfma_f32_16x16x32_bf16( \
            af[mf], bq[nf], acc[mf][nf], 0, 0, 0); \
    __builtin_amdgcn_s_setprio(0); \
  } while (0)

#define PHASE(c, o, kh, aoffn, boffn) do { \
    { const char* aCur = LDS + (c)*32768 + (kh)*16384 + aRd; \
      const char* bCur = LDS + 65536 + (c)*32768 + (kh)*16384 + bRd; \
      LOAD4(af, aCur); \
      LOAD4(bq, bCur); } \
    STAGE_A(o, kh, aoffn); \
    STAGE_B(o, kh, boffn); \
    VMCNT(2); \
    BARRIER(); \
    LGKM0(); \
    MMALL(); \
  } while (0)

__global__ __launch_bounds__(1024, 4) void k_conv(const __bf16* __restrict__ cwt,
                                                  const __bf16* __restrict__ xpad,
                                                  float* __restrict__ out) {
    extern __shared__ __align__(16) char LDS[];

    // XCD swizzle: 416 = 8 * 52 (bijective)
    int flat = blockIdx.x;
    int logical = (flat & 7) * 52 + (flat >> 3);
    int b  = logical / 13;
    int nt = logical - b * 13;

    int tid = threadIdx.x;
    int ln  = tid & 63;
    int wid = tid >> 6;          // 0..15
    int wr  = wid >> 2;          // 0..3: M quarter
    int wc  = wid & 3;           // 0..3: N quarter
    int fr  = ln & 15;
    int kw  = ln >> 4;           // 0..3: 16B k-chunk
    int xsw = ((fr >> 1) & 3) << 4;   // involution within the 64B row

    const char *gA, *gB;
    {
        const char* cwb = (const char*)(cwt + (size_t)b * COUT * KTOT);
        const char* xpb = (const char*)(xpad + (size_t)b * XPP * CIN);
        int L = tid * 16;                    // 0..16383: chunk offset in slab
        int U = L ^ (((L >> 7) & 3) << 4);   // same involution as reads
        int rowU = U >> 6;                   // 0..255
        int kbU  = U & 63;
        gA = cwb + (size_t)rowU * (KTOT * 2) + kbU;
        int p = nt * 256 + rowU; if (p > HW - 1) p = HW - 1;
        int y = p / WW, x = p - y * WW;
        gB = xpb + (size_t)(y * XP + x) * (CIN * 2) + kbU;
    }

    int aRd = (wr * 64 + fr) * 64 + ((kw * 16) ^ xsw);
    int bRd = (wc * 64 + fr) * 64 + ((kw * 16) ^ xsw);

    f32x4 acc[4][4];
    #pragma unroll
    for (int i = 0; i < 4; ++i)
        #pragma unroll
        for (int j = 0; j < 4; ++j)
            acc[i][j] = (f32x4){0.f, 0.f, 0.f, 0.f};

    bf16x8 af[4], bq[4];

    // prologue: stage tile 0 both halves; publish (0,0) pair
    STAGE_A(0, 0, 0);
    STAGE_B(0, 0, 0);
    STAGE_A(0, 1, 0);
    STAGE_B(0, 1, 0);
    VMCNT(2);
    BARRIER();

    for (int kt = 0; kt < NKT - 1; ++kt) {
        int c = kt & 1, o = c ^ 1;
        int ktn  = kt + 1;
        int aoffn = ktn * 128;
        int ktap = ktn >> 2;
        int kyn  = (ktap * 11) >> 5;         // ktap/3 for 0..8
        int kxn  = ktap - kyn * 3;
        int boffn = (kyn * XP + kxn) * 512 + (ktn & 3) * 128;

        PHASE(c, o, 0, aoffn, boffn);
        PHASE(c, o, 1, aoffn, boffn);
    }

    // ---- tail K-tile 35 (buf 1): no stages ----
    {
        const char* aCur = LDS + 32768 + aRd;
        const char* bCur = LDS + 65536 + 32768 + bRd;
        LOAD4(af, aCur); LOAD4(bq, bCur);
        VMCNT(0);
        BARRIER();
        LGKM0();
        MMALL();
        aCur += 16384; bCur += 16384;
        LOAD4(af, aCur); LOAD4(bq, bCur);
        LGKM0();
        MMALL();
    }

    // ---- epilogue: col = lane&15, row = (lane>>4)*4 + reg ----
    float* ob = out + ((size_t)(b * COUT + wr * 64)) * HW;
    int colbase = nt * 256 + wc * 64;
    int rb = (ln >> 4) * 4;
    #pragma unroll
    for (int nf = 0; nf < 4; ++nf) {
        int col = colbase + nf * 16 + fr;
        if (col < HW) {
            #pragma unroll
            for (int mf = 0; mf < 4; ++mf)
                #pragma unroll
                for (int r = 0; r < 4; ++r)
                    ob[(size_t)(mf * 16 + rb + r) * HW + col] = acc[mf][nf][r];
        }
    }
}

// ---------------------------------------------------------------------------
extern "C" void kernel_launch(void* const* d_in, const int* in_sizes, int n_in,
                              void* d_out, int out_size, void* d_ws, size_t ws_size,
                              hipStream_t stream) {
    (void)in_sizes; (void)n_in; (void)out_size; (void)ws_size;
    const float* x   = (const float*)d_in[0];
    const float* we  = (const float*)d_in[1];
    const float* rcw = (const float*)d_in[2];
    const float* rcb = (const float*)d_in[3];
    const float* fcw = (const float*)d_in[4];
    const float* fcb = (const float*)d_in[5];
    float* out = (float*)d_out;

    char* ws = (char*)d_ws;
    float*  rw     = (float*)(ws + OFF_RW);
    float*  pooled = (float*)(ws + OFF_POOLED);
    __bf16* cwt    = (__bf16*)(ws + OFF_CWT);
    __bf16* xpad   = (__bf16*)(ws + OFF_XPAD);

    (void)hipFuncSetAttribute((const void*)k_conv,
                              hipFuncAttributeMaxDynamicSharedMemorySize, 131072);

    k_pre<<<PRE_NBLK, 256, 0, stream>>>(x, pooled, xpad);
    k_route<<<NB, 256, 0, stream>>>(pooled, rcw, rcb, fcw, fcb, rw);
    k_mixw<<<COUT, 256, 0, stream>>>(we, rw, cwt);
    k_conv<<<416, 1024, 131072, stream>>>(cwt, xpad, out);
}

// Round 22
// 208.366 us; speedup vs baseline: 1.0555x; 1.0555x over previous
//
#include <hip/hip_runtime.h>
#include <hip/hip_bf16.h>
#include <stdint.h>

#define NB   32
#define CIN  256
#define COUT 256
#define WW   56
#define HW   3136
#define NEXP 3
#define KTOT 2304          // 9 * 256
#define XP   58
#define XPP  3364          // 58*58
#define NKT  36            // K-tiles of 64

typedef __attribute__((ext_vector_type(8)))  __bf16 bf16x8;
typedef __attribute__((ext_vector_type(4)))  float  f32x4;
typedef __attribute__((ext_vector_type(16))) float  f32x16;

// workspace layout (bytes)
#define OFF_RW     0
#define OFF_POOLED 1024
#define OFF_CWT    (1024 + 32*256*16*4)
#define CWT_BYTES  ((size_t)NB*COUT*KTOT*2)
#define OFF_XPAD   (OFF_CWT + CWT_BYTES)

// ---------------- fused prologue: xpad + pool + zborder (disjoint ranges) ---
#define PRE_XPAD 6272
#define PRE_POOL 8192
#define PRE_NBLK (PRE_XPAD + PRE_POOL + NB)

__global__ __launch_bounds__(256) void k_pre(const float* __restrict__ x,
                                             float* __restrict__ pooled,
                                             __bf16* __restrict__ xpad) {
    __shared__ __align__(16) char smem[8448];
    int blk = blockIdx.x;
    int t = threadIdx.x;

    if (blk < PRE_XPAD) {
        int pt = blk % 49;
        int r2 = blk / 49;
        int ct = r2 & 3;
        int b  = r2 >> 2;
        __bf16 (*lds)[66] = (__bf16(*)[66])smem;
        int pl = t & 63;
        int cb = t >> 6;
        const float* xb = x + ((size_t)(b * CIN + ct * 64)) * HW + pt * 64;
        #pragma unroll
        for (int ic = 0; ic < 16; ++ic) {
            int cl = ic * 4 + cb;
            lds[cl][pl] = (__bf16)xb[(size_t)cl * HW + pl];
        }
        __syncthreads();
        #pragma unroll
        for (int iw = 0; iw < 2; ++iw) {
            int idx = iw * 256 + t;
            int p_l = idx >> 3, c8 = (idx & 7) * 8;
            int p = pt * 64 + p_l;
            int y = p / WW, xx = p - y * WW;
            union { __bf16 h[8]; uint4 u; } pk;
            #pragma unroll
            for (int j = 0; j < 8; ++j) pk.h[j] = lds[c8 + j][p_l];
            __bf16* dst = xpad + ((size_t)b * XPP + (y + 1) * XP + (xx + 1)) * CIN
                          + ct * 64 + c8;
            *(uint4*)dst = pk.u;
        }
    } else if (blk < PRE_XPAD + PRE_POOL) {
        int j = blk - PRE_XPAD;
        int b = j >> 8, c = j & 255;
        float (*lds)[56] = (float(*)[56])smem;
        const float* xb = x + ((size_t)(b * CIN + c)) * HW;
        if (t < 224) {
            int xc = t % 56, yg = t / 56;
            const float* p = xb + (yg * 14) * WW + xc;
            float s = 0.f;
            #pragma unroll
            for (int r = 0; r < 14; ++r) s += p[r * WW];
            lds[yg][xc] = s;
        }
        __syncthreads();
        if (t < 16) {
            int sy = t >> 2, sx = t & 3;
            float s = 0.f;
            #pragma unroll
            for (int jj = 0; jj < 14; ++jj) s += lds[sy][sx * 14 + jj];
            pooled[(((size_t)b * CIN + c) << 4) + t] = s * (1.f / 196.f);
        }
    } else {
        int b = blk - (PRE_XPAD + PRE_POOL);
        for (int idx = t; idx < 228 * 32; idx += 256) {
            int pos = idx >> 5;
            int co = (idx & 31) * 8;
            int yy, xx;
            if (pos < 58)       { yy = 0;          xx = pos; }
            else if (pos < 116) { yy = 57;         xx = pos - 58; }
            else if (pos < 172) { yy = pos - 115;  xx = 0; }
            else                { yy = pos - 171;  xx = 57; }
            uint4 z = {0u, 0u, 0u, 0u};
            *(uint4*)(xpad + ((size_t)b * XPP + yy * XP + xx) * CIN + co) = z;
        }
    }
}

// ---------------- routing ---------------------------------------------------
__global__ __launch_bounds__(256) void k_route(const float* __restrict__ pooled,
                                               const float* __restrict__ rcw,
                                               const float* __restrict__ rcb,
                                               const float* __restrict__ fcw,
                                               const float* __restrict__ fcb,
                                               float* __restrict__ rw) {
    int b = blockIdx.x;
    int t = threadIdx.x;
    int r = t >> 4, ij = t & 15;
    __shared__ float rbuf[256];
    const float* pb = pooled + (size_t)b * CIN * 16;
    float acc = rcb[r];
    for (int c = 0; c < CIN; ++c)
        acc += pb[c * 16 + ij] * rcw[r * CIN + c];
    rbuf[t] = fmaxf(acc, 0.f);
    __syncthreads();
    if (t < NEXP) {
        float a = fcb[t];
        for (int f = 0; f < 256; ++f) a += rbuf[f] * fcw[t * 256 + f];
        a = fmaxf(a, 0.f);
        rw[b * NEXP + t] = 1.f / (1.f + expf(-a));
    }
}

// ---------------- weight mixing (original register-cached version) ----------
__global__ __launch_bounds__(256) void k_mixw(const float* __restrict__ we,
                                              const float* __restrict__ rw,
                                              __bf16* __restrict__ cwt) {
    int o = blockIdx.x;
    int i = threadIdx.x;
    float wv[3][9];
    #pragma unroll
    for (int e = 0; e < 3; ++e) {
        const float* p = we + (((size_t)e * COUT + o) * CIN + i) * 9;
        #pragma unroll
        for (int k = 0; k < 9; ++k) wv[e][k] = p[k];
    }
    for (int b = 0; b < NB; ++b) {
        float r0 = rw[b * 3 + 0], r1 = rw[b * 3 + 1], r2 = rw[b * 3 + 2];
        __bf16* op = cwt + ((size_t)(b * COUT + o)) * KTOT + i;
        #pragma unroll
        for (int k = 0; k < 9; ++k) {
            float v = r0 * wv[0][k] + r1 * wv[1][k] + r2 * wv[2][k];
            op[k * 256] = (__bf16)v;
        }
    }
}

// ---------------- implicit-GEMM conv ----------------------------------------
// 256x256 tile, BK=64, 16 waves x 64x64 wave-tiles, 128 KiB LDS, R15
// publication-shifted pipeline UNCHANGED. MFMA shape switched 16x16x32 ->
// **32x32x16** (same LDS bytes: 8 b128 reads/phase; MFMA count 16->8, cycles
// 77.6->64 per phase per wave; 32x32 rate 4096 vs 3378 FLOP/cyc).
// Fragment map (guide 3, m74/m101): A/B operand row = lane&31,
// k = (lane>>5)*8 + j; C/D col = lane&31, row = (reg&3)+8*(reg>>2)+4*(lane>>5).
// Read addr: (waveRow + ln&31)*64 + ((ks*32 + (ln>>5)*16) ^ xsw); xsw from
// row bits 1-2 = ln bits 1-2 (identical algebra to the 16x16 version).
#define GL16(g, l) __builtin_amdgcn_global_load_lds( \
    (const __attribute__((address_space(1))) uint32_t*)(g), \
    (__attribute__((address_space(3))) uint32_t*)(l), 16, 0, 0)

#define STAGE_A(o, kh, aoffn) \
    GL16(gA + (aoffn) + (kh)*64, LDS + (o)*32768 + (kh)*16384 + wid*1024)
#define STAGE_B(o, kh, boffn) \
    GL16(gB + (boffn) + (kh)*64, LDS + 65536 + (o)*32768 + (kh)*16384 + wid*1024)

#define BARRIER() do { \
    __builtin_amdgcn_sched_barrier(0); \
    __builtin_amdgcn_s_barrier(); \
    __builtin_amdgcn_sched_barrier(0); \
  } while (0)
#define VMCNT(n) do { \
    asm volatile("s_waitcnt vmcnt(" #n ")" ::: "memory"); \
    __builtin_amdgcn_sched_barrier(0); \
  } while (0)
#define LGKM0() do { \
    asm volatile("s_waitcnt lgkmcnt(0)" ::: "memory"); \
    __builtin_amdgcn_sched_barrier(0); \
  } while (0)

// 8 b128: aF/bF[MB or NB][ks]
#define READ32(c, kh) do { \
    const char* aCur = LDS + (c)*32768 + (kh)*16384 + aRd; \
    const char* bCur = LDS + 65536 + (c)*32768 + (kh)*16384 + bRd; \
    aF[0][0] = *(const bf16x8*)(aCur + ok0); \
    aF[0][1] = *(const bf16x8*)(aCur + ok1); \
    aF[1][0] = *(const bf16x8*)(aCur + 2048 + ok0); \
    aF[1][1] = *(const bf16x8*)(aCur + 2048 + ok1); \
    bF[0][0] = *(const bf16x8*)(bCur + ok0); \
    bF[0][1] = *(const bf16x8*)(bCur + ok1); \
    bF[1][0] = *(const bf16x8*)(bCur + 2048 + ok0); \
    bF[1][1] = *(const bf16x8*)(bCur + 2048 + ok1); \
    __builtin_amdgcn_sched_barrier(0); \
  } while (0)

#define MM8() do { \
    __builtin_amdgcn_s_setprio(1); \
    _Pragma("unroll") \
    for (int MB = 0; MB < 2; ++MB) \
      _Pragma("unroll") \
      for (int NBl = 0; NBl < 2; ++NBl) { \
        acc[MB][NBl] = __builtin_amdgcn_mfma_f32_32x32x16_bf16( \
            aF[MB][0], bF[NBl][0], acc[MB][NBl], 0, 0, 0); \
        acc[MB][NBl] = __builtin_amdgcn_mfma_f32_32x32x16_bf16( \
            aF[MB][1], bF[NBl][1], acc[MB][NBl], 0, 0, 0); \
      } \
    __builtin_amdgcn_s_setprio(0); \
  } while (0)

#define PHASE(c, o, kh, aoffn, boffn) do { \
    READ32(c, kh); \
    STAGE_A(o, kh, aoffn); \
    STAGE_B(o, kh, boffn); \
    VMCNT(2); \
    BARRIER(); \
    LGKM0(); \
    MM8(); \
  } while (0)

__global__ __launch_bounds__(1024, 4) void k_conv(const __bf16* __restrict__ cwt,
                                                  const __bf16* __restrict__ xpad,
                                                  float* __restrict__ out) {
    extern __shared__ __align__(16) char LDS[];

    // XCD swizzle: 416 = 8 * 52 (bijective)
    int flat = blockIdx.x;
    int logical = (flat & 7) * 52 + (flat >> 3);
    int b  = logical / 13;
    int nt = logical - b * 13;

    int tid = threadIdx.x;
    int ln  = tid & 63;
    int wid = tid >> 6;          // 0..15
    int wr  = wid >> 2;          // 0..3: M quarter (rows wr*64..+64)
    int wc  = wid & 3;           // 0..3: N quarter (cols wc*64..+64)
    int xsw = ((ln >> 1) & 3) << 4;   // involution within the 64B row

    const char *gA, *gB;
    {
        const char* cwb = (const char*)(cwt + (size_t)b * COUT * KTOT);
        const char* xpb = (const char*)(xpad + (size_t)b * XPP * CIN);
        int L = tid * 16;                    // 0..16383: chunk offset in slab
        int U = L ^ (((L >> 7) & 3) << 4);   // same involution as reads
        int rowU = U >> 6;                   // 0..255
        int kbU  = U & 63;
        gA = cwb + (size_t)rowU * (KTOT * 2) + kbU;
        int p = nt * 256 + rowU; if (p > HW - 1) p = HW - 1;
        int y = p / WW, x = p - y * WW;
        gB = xpb + (size_t)(y * XP + x) * (CIN * 2) + kbU;
    }

    int aRd = (wr * 64 + (ln & 31)) * 64;
    int bRd = (wc * 64 + (ln & 31)) * 64;
    int hi16 = (ln >> 5) * 16;
    int ok0 = (0  + hi16) ^ xsw;     // ks=0 byte offset within 64B row
    int ok1 = (32 + hi16) ^ xsw;     // ks=1

    f32x16 acc[2][2];
    #pragma unroll
    for (int i = 0; i < 2; ++i)
        #pragma unroll
        for (int j = 0; j < 2; ++j)
            acc[i][j] = (f32x16)(0.f);

    bf16x8 aF[2][2], bF[2][2];

    // prologue: stage tile 0 both halves; publish (0,0) pair
    STAGE_A(0, 0, 0);
    STAGE_B(0, 0, 0);
    STAGE_A(0, 1, 0);
    STAGE_B(0, 1, 0);
    VMCNT(2);
    BARRIER();

    for (int kt = 0; kt < NKT - 1; ++kt) {
        int c = kt & 1, o = c ^ 1;
        int ktn  = kt + 1;
        int aoffn = ktn * 128;
        int ktap = ktn >> 2;
        int kyn  = (ktap * 11) >> 5;         // ktap/3 for 0..8
        int kxn  = ktap - kyn * 3;
        int boffn = (kyn * XP + kxn) * 512 + (ktn & 3) * 128;

        PHASE(c, o, 0, aoffn, boffn);
        PHASE(c, o, 1, aoffn, boffn);
    }

    // ---- tail K-tile 35 (buf 1): no stages ----
    {
        READ32(1, 0);
        VMCNT(0);
        BARRIER();
        LGKM0();
        MM8();
        READ32(1, 1);
        LGKM0();
        MM8();
    }

    // ---- epilogue: col = lane&31, row = (reg&3)+8*(reg>>2)+4*(lane>>5) ----
    float* ob = out + ((size_t)(b * COUT + wr * 64)) * HW;
    int colbase = nt * 256 + wc * 64;
    int rbase = (ln >> 5) * 4;
    #pragma unroll
    for (int NBl = 0; NBl < 2; ++NBl) {
        int col = colbase + NBl * 32 + (ln & 31);
        if (col < HW) {
            #pragma unroll
            for (int MB = 0; MB < 2; ++MB)
                #pragma unroll
                for (int reg = 0; reg < 16; ++reg) {
                    int row = MB * 32 + (reg & 3) + 8 * (reg >> 2) + rbase;
                    ob[(size_t)row * HW + col] = acc[MB][NBl][reg];
                }
        }
    }
}

// ---------------------------------------------------------------------------
extern "C" void kernel_launch(void* const* d_in, const int* in_sizes, int n_in,
                              void* d_out, int out_size, void* d_ws, size_t ws_size,
                              hipStream_t stream) {
    (void)in_sizes; (void)n_in; (void)out_size; (void)ws_size;
    const float* x   = (const float*)d_in[0];
    const float* we  = (const float*)d_in[1];
    const float* rcw = (const float*)d_in[2];
    const float* rcb = (const float*)d_in[3];
    const float* fcw = (const float*)d_in[4];
    const float* fcb = (const float*)d_in[5];
    float* out = (float*)d_out;

    char* ws = (char*)d_ws;
    float*  rw     = (float*)(ws + OFF_RW);
    float*  pooled = (float*)(ws + OFF_POOLED);
    __bf16* cwt    = (__bf16*)(ws + OFF_CWT);
    __bf16* xpad   = (__bf16*)(ws + OFF_XPAD);

    (void)hipFuncSetAttribute((const void*)k_conv,
                              hipFuncAttributeMaxDynamicSharedMemorySize, 131072);

    k_pre<<<PRE_NBLK, 256, 0, stream>>>(x, pooled, xpad);
    k_route<<<NB, 256, 0, stream>>>(pooled, rcw, rcb, fcw, fcb, rw);
    k_mixw<<<COUT, 256, 0, stream>>>(we, rw, cwt);
    k_conv<<<416, 1024, 131072, stream>>>(cwt, xpad, out);
}

// Round 23
// 194.824 us; speedup vs baseline: 1.1289x; 1.0695x over previous
//
#include <hip/hip_runtime.h>
#include <hip/hip_bf16.h>
#include <stdint.h>

#define NB   32
#define CIN  256
#define COUT 256
#define WW   56
#define HW   3136
#define NEXP 3
#define KTOT 2304          // 9 * 256
#define XP   58
#define XPP  3364          // 58*58
#define NKT  36            // K-tiles of 64

typedef __attribute__((ext_vector_type(8))) __bf16 bf16x8;
typedef __attribute__((ext_vector_type(4))) float  f32x4;

// workspace layout (bytes)
#define OFF_RW     0
#define OFF_POOLED 1024
#define OFF_CWT    (1024 + 32*256*16*4)
#define CWT_BYTES  ((size_t)NB*COUT*KTOT*2)
#define OFF_XPAD   (OFF_CWT + CWT_BYTES)

// ---------------- fused prologue: xpad + pool + zborder (disjoint ranges) ---
#define PRE_XPAD 6272
#define PRE_POOL 8192
#define PRE_NBLK (PRE_XPAD + PRE_POOL + NB)

__global__ __launch_bounds__(256) void k_pre(const float* __restrict__ x,
                                             float* __restrict__ pooled,
                                             __bf16* __restrict__ xpad) {
    __shared__ __align__(16) char smem[8448];
    int blk = blockIdx.x;
    int t = threadIdx.x;

    if (blk < PRE_XPAD) {
        int pt = blk % 49;
        int r2 = blk / 49;
        int ct = r2 & 3;
        int b  = r2 >> 2;
        __bf16 (*lds)[66] = (__bf16(*)[66])smem;
        int pl = t & 63;
        int cb = t >> 6;
        const float* xb = x + ((size_t)(b * CIN + ct * 64)) * HW + pt * 64;
        #pragma unroll
        for (int ic = 0; ic < 16; ++ic) {
            int cl = ic * 4 + cb;
            lds[cl][pl] = (__bf16)xb[(size_t)cl * HW + pl];
        }
        __syncthreads();
        #pragma unroll
        for (int iw = 0; iw < 2; ++iw) {
            int idx = iw * 256 + t;
            int p_l = idx >> 3, c8 = (idx & 7) * 8;
            int p = pt * 64 + p_l;
            int y = p / WW, xx = p - y * WW;
            union { __bf16 h[8]; uint4 u; } pk;
            #pragma unroll
            for (int j = 0; j < 8; ++j) pk.h[j] = lds[c8 + j][p_l];
            __bf16* dst = xpad + ((size_t)b * XPP + (y + 1) * XP + (xx + 1)) * CIN
                          + ct * 64 + c8;
            *(uint4*)dst = pk.u;
        }
    } else if (blk < PRE_XPAD + PRE_POOL) {
        int j = blk - PRE_XPAD;
        int b = j >> 8, c = j & 255;
        float (*lds)[56] = (float(*)[56])smem;
        const float* xb = x + ((size_t)(b * CIN + c)) * HW;
        if (t < 224) {
            int xc = t % 56, yg = t / 56;
            const float* p = xb + (yg * 14) * WW + xc;
            float s = 0.f;
            #pragma unroll
            for (int r = 0; r < 14; ++r) s += p[r * WW];
            lds[yg][xc] = s;
        }
        __syncthreads();
        if (t < 16) {
            int sy = t >> 2, sx = t & 3;
            float s = 0.f;
            #pragma unroll
            for (int jj = 0; jj < 14; ++jj) s += lds[sy][sx * 14 + jj];
            pooled[(((size_t)b * CIN + c) << 4) + t] = s * (1.f / 196.f);
        }
    } else {
        int b = blk - (PRE_XPAD + PRE_POOL);
        for (int idx = t; idx < 228 * 32; idx += 256) {
            int pos = idx >> 5;
            int co = (idx & 31) * 8;
            int yy, xx;
            if (pos < 58)       { yy = 0;          xx = pos; }
            else if (pos < 116) { yy = 57;         xx = pos - 58; }
            else if (pos < 172) { yy = pos - 115;  xx = 0; }
            else                { yy = pos - 171;  xx = 57; }
            uint4 z = {0u, 0u, 0u, 0u};
            *(uint4*)(xpad + ((size_t)b * XPP + yy * XP + xx) * CIN + co) = z;
        }
    }
}

// ---------------- routing ---------------------------------------------------
__global__ __launch_bounds__(256) void k_route(const float* __restrict__ pooled,
                                               const float* __restrict__ rcw,
                                               const float* __restrict__ rcb,
                                               const float* __restrict__ fcw,
                                               const float* __restrict__ fcb,
                                               float* __restrict__ rw) {
    int b = blockIdx.x;
    int t = threadIdx.x;
    int r = t >> 4, ij = t & 15;
    __shared__ float rbuf[256];
    const float* pb = pooled + (size_t)b * CIN * 16;
    float acc = rcb[r];
    for (int c = 0; c < CIN; ++c)
        acc += pb[c * 16 + ij] * rcw[r * CIN + c];
    rbuf[t] = fmaxf(acc, 0.f);
    __syncthreads();
    if (t < NEXP) {
        float a = fcb[t];
        for (int f = 0; f < 256; ++f) a += rbuf[f] * fcw[t * 256 + f];
        a = fmaxf(a, 0.f);
        rw[b * NEXP + t] = 1.f / (1.f + expf(-a));
    }
}

// ---------------- weight mixing (register-cached, coalesced) ----------------
__global__ __launch_bounds__(256) void k_mixw(const float* __restrict__ we,
                                              const float* __restrict__ rw,
                                              __bf16* __restrict__ cwt) {
    int o = blockIdx.x;
    int i = threadIdx.x;
    float wv[3][9];
    #pragma unroll
    for (int e = 0; e < 3; ++e) {
        const float* p = we + (((size_t)e * COUT + o) * CIN + i) * 9;
        #pragma unroll
        for (int k = 0; k < 9; ++k) wv[e][k] = p[k];
    }
    for (int b = 0; b < NB; ++b) {
        float r0 = rw[b * 3 + 0], r1 = rw[b * 3 + 1], r2 = rw[b * 3 + 2];
        __bf16* op = cwt + ((size_t)(b * COUT + o)) * KTOT + i;
        #pragma unroll
        for (int k = 0; k < 9; ++k) {
            float v = r0 * wv[0][k] + r1 * wv[1][k] + r2 * wv[2][k];
            op[k * 256] = (__bf16)v;
        }
    }
}

// ---------------- implicit-GEMM conv (best measured: R15) -------------------
// 256x256 tile, BK=64, 16 waves x 64x64 wave-tiles, 128 KiB LDS.
// Publication-shifted phase: {reads (c,kh) -> stages (o,kh) -> VMCNT(2) ->
// barrier -> lgkm0 -> 16-MFMA}. VMCNT(2) retires the pair staged in the
// PREVIOUS phase (the slabs the NEXT phase reads); the barrier publishes
// them (all-waves vmcnt + barrier = race-free). Outstanding/thread:
// 2 -> 4 -> VMCNT(2) -> 2. Prologue: 4 stages, VMCNT(2), barrier.
// Tail: VMCNT(0)+barrier between its two halves.
// WAR: slab overwrite-stage is 2 barriers after its last reads retired.
#define GL16(g, l) __builtin_amdgcn_global_load_lds( \
    (const __attribute__((address_space(1))) uint32_t*)(g), \
    (__attribute__((address_space(3))) uint32_t*)(l), 16, 0, 0)

#define STAGE_A(o, kh, aoffn) \
    GL16(gA + (aoffn) + (kh)*64, LDS + (o)*32768 + (kh)*16384 + wid*1024)
#define STAGE_B(o, kh, boffn) \
    GL16(gB + (boffn) + (kh)*64, LDS + 65536 + (o)*32768 + (kh)*16384 + wid*1024)

#define BARRIER() do { \
    __builtin_amdgcn_sched_barrier(0); \
    __builtin_amdgcn_s_barrier(); \
    __builtin_amdgcn_sched_barrier(0); \
  } while (0)
#define VMCNT(n) do { \
    asm volatile("s_waitcnt vmcnt(" #n ")" ::: "memory"); \
    __builtin_amdgcn_sched_barrier(0); \
  } while (0)
#define LGKM0() do { \
    asm volatile("s_waitcnt lgkmcnt(0)" ::: "memory"); \
    __builtin_amdgcn_sched_barrier(0); \
  } while (0)

#define LOAD4(F, base) do { \
    F[0] = *(const bf16x8*)((base) + 0); \
    F[1] = *(const bf16x8*)((base) + 1024); \
    F[2] = *(const bf16x8*)((base) + 2048); \
    F[3] = *(const bf16x8*)((base) + 3072); \
  } while (0)
#define MMALL() do { \
    __builtin_amdgcn_s_setprio(1); \
    _Pragma("unroll") \
    for (int mf = 0; mf < 4; ++mf) \
      _Pragma("unroll") \
      for (int nf = 0; nf < 4; ++nf) \
        acc[mf][nf] = __builtin_amdgcn_mfma_f32_16x16x32_bf16( \
            af[mf], bq[nf], acc[mf][nf], 0, 0, 0); \
    __builtin_amdgcn_s_setprio(0); \
  } while (0)

#define PHASE(c, o, kh, aoffn, boffn) do { \
    { const char* aCur = LDS + (c)*32768 + (kh)*16384 + aRd; \
      const char* bCur = LDS + 65536 + (c)*32768 + (kh)*16384 + bRd; \
      LOAD4(af, aCur); \
      LOAD4(bq, bCur); } \
    STAGE_A(o, kh, aoffn); \
    STAGE_B(o, kh, boffn); \
    VMCNT(2); \
    BARRIER(); \
    LGKM0(); \
    MMALL(); \
  } while (0)

__global__ __launch_bounds__(1024, 4) void k_conv(const __bf16* __restrict__ cwt,
                                                  const __bf16* __restrict__ xpad,
                                                  float* __restrict__ out) {
    extern __shared__ __align__(16) char LDS[];

    // XCD swizzle: 416 = 8 * 52 (bijective)
    int flat = blockIdx.x;
    int logical = (flat & 7) * 52 + (flat >> 3);
    int b  = logical / 13;
    int nt = logical - b * 13;

    int tid = threadIdx.x;
    int ln  = tid & 63;
    int wid = tid >> 6;          // 0..15
    int wr  = wid >> 2;          // 0..3: M quarter
    int wc  = wid & 3;           // 0..3: N quarter
    int fr  = ln & 15;
    int kw  = ln >> 4;           // 0..3: 16B k-chunk
    int xsw = ((fr >> 1) & 3) << 4;   // involution within the 64B row

    const char *gA, *gB;
    {
        const char* cwb = (const char*)(cwt + (size_t)b * COUT * KTOT);
        const char* xpb = (const char*)(xpad + (size_t)b * XPP * CIN);
        int L = tid * 16;                    // 0..16383: chunk offset in slab
        int U = L ^ (((L >> 7) & 3) << 4);   // same involution as reads
        int rowU = U >> 6;                   // 0..255
        int kbU  = U & 63;
        gA = cwb + (size_t)rowU * (KTOT * 2) + kbU;
        int p = nt * 256 + rowU; if (p > HW - 1) p = HW - 1;
        int y = p / WW, x = p - y * WW;
        gB = xpb + (size_t)(y * XP + x) * (CIN * 2) + kbU;
    }

    int aRd = (wr * 64 + fr) * 64 + ((kw * 16) ^ xsw);
    int bRd = (wc * 64 + fr) * 64 + ((kw * 16) ^ xsw);

    f32x4 acc[4][4];
    #pragma unroll
    for (int i = 0; i < 4; ++i)
        #pragma unroll
        for (int j = 0; j < 4; ++j)
            acc[i][j] = (f32x4){0.f, 0.f, 0.f, 0.f};

    bf16x8 af[4], bq[4];

    // prologue: stage tile 0 both halves; publish (0,0) pair
    STAGE_A(0, 0, 0);
    STAGE_B(0, 0, 0);
    STAGE_A(0, 1, 0);
    STAGE_B(0, 1, 0);
    VMCNT(2);
    BARRIER();

    for (int kt = 0; kt < NKT - 1; ++kt) {
        int c = kt & 1, o = c ^ 1;
        int ktn  = kt + 1;
        int aoffn = ktn * 128;
        int ktap = ktn >> 2;
        int kyn  = (ktap * 11) >> 5;         // ktap/3 for 0..8
        int kxn  = ktap - kyn * 3;
        int boffn = (kyn * XP + kxn) * 512 + (ktn & 3) * 128;

        PHASE(c, o, 0, aoffn, boffn);
        PHASE(c, o, 1, aoffn, boffn);
    }

    // ---- tail K-tile 35 (buf 1): no stages ----
    {
        const char* aCur = LDS + 32768 + aRd;
        const char* bCur = LDS + 65536 + 32768 + bRd;
        LOAD4(af, aCur); LOAD4(bq, bCur);
        VMCNT(0);
        BARRIER();
        LGKM0();
        MMALL();
        aCur += 16384; bCur += 16384;
        LOAD4(af, aCur); LOAD4(bq, bCur);
        LGKM0();
        MMALL();
    }

    // ---- epilogue: col = lane&15, row = (lane>>4)*4 + reg ----
    float* ob = out + ((size_t)(b * COUT + wr * 64)) * HW;
    int colbase = nt * 256 + wc * 64;
    int rb = (ln >> 4) * 4;
    #pragma unroll
    for (int nf = 0; nf < 4; ++nf) {
        int col = colbase + nf * 16 + fr;
        if (col < HW) {
            #pragma unroll
            for (int mf = 0; mf < 4; ++mf)
                #pragma unroll
                for (int r = 0; r < 4; ++r)
                    ob[(size_t)(mf * 16 + rb + r) * HW + col] = acc[mf][nf][r];
        }
    }
}

// ---------------------------------------------------------------------------
extern "C" void kernel_launch(void* const* d_in, const int* in_sizes, int n_in,
                              void* d_out, int out_size, void* d_ws, size_t ws_size,
                              hipStream_t stream) {
    (void)in_sizes; (void)n_in; (void)out_size; (void)ws_size;
    const float* x   = (const float*)d_in[0];
    const float* we  = (const float*)d_in[1];
    const float* rcw = (const float*)d_in[2];
    const float* rcb = (const float*)d_in[3];
    const float* fcw = (const float*)d_in[4];
    const float* fcb = (const float*)d_in[5];
    float* out = (float*)d_out;

    char* ws = (char*)d_ws;
    float*  rw     = (float*)(ws + OFF_RW);
    float*  pooled = (float*)(ws + OFF_POOLED);
    __bf16* cwt    = (__bf16*)(ws + OFF_CWT);
    __bf16* xpad   = (__bf16*)(ws + OFF_XPAD);

    (void)hipFuncSetAttribute((const void*)k_conv,
                              hipFuncAttributeMaxDynamicSharedMemorySize, 131072);

    k_pre<<<PRE_NBLK, 256, 0, stream>>>(x, pooled, xpad);
    k_route<<<NB, 256, 0, stream>>>(pooled, rcw, rcb, fcw, fcb, rw);
    k_mixw<<<COUT, 256, 0, stream>>>(we, rw, cwt);
    k_conv<<<416, 1024, 131072, stream>>>(cwt, xpad, out);
}